// Round 1
// baseline (304.945 us; speedup 1.0000x reference)
//
#include <hip/hip_runtime.h>
#include <hip/hip_bf16.h>

using f32x4  = __attribute__((ext_vector_type(4))) float;
using u32x4  = __attribute__((ext_vector_type(4))) unsigned int;
using bf16x8 = __attribute__((ext_vector_type(8))) short;

__device__ __forceinline__ ushort f2bf(float x) {
    union { __hip_bfloat16 h; ushort u; } cv;
    cv.h = __float2bfloat16(x);
    return cv.u;
}
__device__ __forceinline__ float sigmoidf_(float x) { return 1.f / (1.f + expf(-x)); }

// ---------------------------------------------------------------------------
// Generic GEMM: C[M,N] = A(f32,[M,K]) * B(bf16,[K,N]) (+bias, relu, bf16/f32 out)
// BM=128, BN=64, BK=32. 256 threads = 4 waves (2x2), wave tile 64x32.
// A converted f32->bf16 during staging. B transposed into LDS.
// SPLIT: blockIdx.z selects K-chunk, writes f32 partial at P + z*M*N.
// ---------------------------------------------------------------------------
template<bool SPLIT, bool RELU, bool BF16_OUT, bool HAS_BIAS>
__global__ __launch_bounds__(256)
void gemm_kernel(const float* __restrict__ A, const ushort* __restrict__ B,
                 const float* __restrict__ bias, float* __restrict__ Cf,
                 ushort* __restrict__ Cb, int M, int N, int K, int ldc, int kPerChunk)
{
    __shared__ ushort As[128 * 40];
    __shared__ ushort Bs[64 * 40];
    const int tid  = threadIdx.x;
    const int lane = tid & 63;
    const int wid  = tid >> 6;
    const int wr   = wid >> 1, wc = wid & 1;
    const int g    = lane >> 4, lr = lane & 15;
    const long m0  = (long)blockIdx.x * 128;
    const int  n0  = blockIdx.y * 64;

    int kbeg = 0, kend = K;
    if (SPLIT) { kbeg = blockIdx.z * kPerChunk; kend = kbeg + kPerChunk; if (kend > K) kend = K; }

    const int bkr = tid & 31;   // B k-row within tile
    const int bcb = tid >> 5;   // B col-octet

    f32x4 pa[4];
    u32x4 pb;
    const float* Abase = A + m0 * (long)K;

    auto loadT = [&](int k0) {
#pragma unroll
        for (int i = 0; i < 4; i++) {
            int s = tid + 256 * i; int row = s >> 3, c4 = s & 7;
            pa[i] = *(const f32x4*)(Abase + (long)row * K + k0 + c4 * 4);
        }
        pb = *(const u32x4*)(B + (long)(k0 + bkr) * N + n0 + bcb * 8);
    };
    auto storeT = [&]() {
#pragma unroll
        for (int i = 0; i < 4; i++) {
            int s = tid + 256 * i; int row = s >> 3, c4 = s & 7;
            ushort4 w;
            w.x = f2bf(pa[i].x); w.y = f2bf(pa[i].y);
            w.z = f2bf(pa[i].z); w.w = f2bf(pa[i].w);
            *(ushort4*)(&As[row * 40 + c4 * 4]) = w;
        }
        const ushort* p8 = (const ushort*)&pb;
#pragma unroll
        for (int j = 0; j < 8; j++) Bs[(bcb * 8 + j) * 40 + bkr] = p8[j];
    };

    f32x4 acc[4][2] = {};

    const int nk = (kend - kbeg) >> 5;
    loadT(kbeg);
    for (int t = 0; t < nk; ++t) {
        storeT();
        __syncthreads();
        if (t + 1 < nk) loadT(kbeg + ((t + 1) << 5));
        bf16x8 af[4], bfr[2];
#pragma unroll
        for (int fm = 0; fm < 4; fm++)
            af[fm] = *(const bf16x8*)(&As[(wr * 64 + fm * 16 + lr) * 40 + g * 8]);
#pragma unroll
        for (int fn = 0; fn < 2; fn++)
            bfr[fn] = *(const bf16x8*)(&Bs[(wc * 32 + fn * 16 + lr) * 40 + g * 8]);
#pragma unroll
        for (int fm = 0; fm < 4; fm++)
#pragma unroll
            for (int fn = 0; fn < 2; fn++)
                acc[fm][fn] = __builtin_amdgcn_mfma_f32_16x16x32_bf16(af[fm], bfr[fn], acc[fm][fn], 0, 0, 0);
        __syncthreads();
    }

    if (SPLIT) {
        float* P = Cf + (long)blockIdx.z * M * N;
#pragma unroll
        for (int fm = 0; fm < 4; fm++)
#pragma unroll
            for (int fn = 0; fn < 2; fn++)
#pragma unroll
                for (int rr = 0; rr < 4; rr++) {
                    long row = m0 + wr * 64 + fm * 16 + g * 4 + rr;
                    int  col = n0 + wc * 32 + fn * 16 + lr;
                    P[row * N + col] = acc[fm][fn][rr];
                }
    } else {
#pragma unroll
        for (int fm = 0; fm < 4; fm++)
#pragma unroll
            for (int fn = 0; fn < 2; fn++)
#pragma unroll
                for (int rr = 0; rr < 4; rr++) {
                    long row = m0 + wr * 64 + fm * 16 + g * 4 + rr;
                    int  col = n0 + wc * 32 + fn * 16 + lr;
                    float v = acc[fm][fn][rr];
                    if (HAS_BIAS) v += bias[col];
                    if (RELU) v = fmaxf(v, 0.f);
                    if (BF16_OUT) Cb[row * ldc + col] = f2bf(v);
                    else          Cf[row * ldc + col] = v;
                }
    }
}

__global__ __launch_bounds__(256) void reduce_add(const float* __restrict__ P,
                                                  float* __restrict__ C, int MN, int nz)
{
    int i = blockIdx.x * 256 + threadIdx.x;
    int n4 = MN >> 2;
    if (i >= n4) return;
    f32x4 a = ((const f32x4*)P)[i];
    for (int z = 1; z < nz; z++) a += ((const f32x4*)(P + (long)z * MN))[i];
    ((f32x4*)C)[i] = a;
}

// f32 -> bf16 same layout (n4 = elems/4)
__global__ void convert_bf16_k(const float* __restrict__ X, ushort* __restrict__ Y, int n4)
{
    int j = blockIdx.x * 256 + threadIdx.x;
    if (j >= n4) return;
    f32x4 v = ((const f32x4*)X)[j];
    ushort4 o; o.x = f2bf(v.x); o.y = f2bf(v.y); o.z = f2bf(v.z); o.w = f2bf(v.w);
    ((ushort4*)Y)[j] = o;
}

// W[O][I] f32 -> T[I][O] bf16
__global__ void transpose_bf16_k(const float* __restrict__ W, ushort* __restrict__ T, int O, int I)
{
    int j = blockIdx.x * 256 + threadIdx.x;
    if (j >= O * I) return;
    int i = j / O, o = j - i * O;
    T[j] = f2bf(W[(long)o * I + i]);
}

__global__ void zero_stats_k(float* stats) { if (threadIdx.x < 192) stats[threadIdx.x] = 0.f; }

// per-column sum / sumsq of Zc[8192][64]; grid 64 x 256
__global__ __launch_bounds__(256) void bn_stats_k(const float* __restrict__ Zc,
                                                  float* __restrict__ gsum, float* __restrict__ gsq)
{
    int b = blockIdx.x, t = threadIdx.x;
    int c = t & 63, rg = t >> 6;
    float sx = 0.f, sq = 0.f;
    int base = b * 128 + rg;
#pragma unroll 8
    for (int i = 0; i < 32; i++) {
        float x = Zc[(base + 4 * i) * 64 + c];
        sx += x; sq += x * x;
    }
    __shared__ float ls[256], lq[256];
    ls[t] = sx; lq[t] = sq;
    __syncthreads();
    if (t < 64) {
        float a = ls[t] + ls[t + 64] + ls[t + 128] + ls[t + 192];
        float q = lq[t] + lq[t + 64] + lq[t + 128] + lq[t + 192];
        atomicAdd(&gsum[t], a);
        atomicAdd(&gsq[t], q);
    }
}

// Z1[row] = max_c relu(bn(Zc1[row,c])); wave per row, grid 2048 x 256
__global__ __launch_bounds__(256) void z1_k(const float* __restrict__ Zc,
                                            const float* __restrict__ gsum, const float* __restrict__ gsq,
                                            const float* __restrict__ g, const float* __restrict__ b,
                                            float* __restrict__ Z1)
{
    int w = threadIdx.x >> 6, lane = threadIdx.x & 63;
    int row = blockIdx.x * 4 + w;
    const float inv = 1.f / 8192.f;
    float m = gsum[lane] * inv;
    float v = gsq[lane] * inv - m * m;
    float x = Zc[row * 64 + lane];
    float y = fmaxf(g[lane] * (x - m) * rsqrtf(v + 1e-5f) + b[lane], 0.f);
#pragma unroll
    for (int o = 32; o > 0; o >>= 1) y = fmaxf(y, __shfl_xor(y, o));
    if (lane == 0) Z1[row] = y;
}

// s[i] = L1[i,:] . Z1 ; r[i] = sum_j L1[i,j]; grid 8192 x 256
__global__ __launch_bounds__(256) void pass2_k(const float* __restrict__ L1, const float* __restrict__ Z1,
                                               float* __restrict__ s, float* __restrict__ r)
{
    int i = blockIdx.x, t = threadIdx.x;
    const f32x4* row = (const f32x4*)(L1 + (long)i * 8192);
    const f32x4* z4  = (const f32x4*)Z1;
    float as = 0.f, ar = 0.f;
#pragma unroll
    for (int k = 0; k < 8; k++) {
        f32x4 v = row[t + 256 * k];
        f32x4 z = z4[t + 256 * k];
        as += v.x * z.x + v.y * z.y + v.z * z.z + v.w * z.w;
        ar += v.x + v.y + v.z + v.w;
    }
    __shared__ float ls[256], lr[256];
    ls[t] = as; lr[t] = ar;
    __syncthreads();
    for (int off = 128; off > 0; off >>= 1) {
        if (t < off) { ls[t] += ls[t + off]; lr[t] += lr[t + off]; }
        __syncthreads();
    }
    if (t == 0) { s[i] = ls[0]; r[i] = lr[0]; }
}

// sums of s, r, s^2, r^2, s*r over 8192; grid 32 x 256 into S[0..4]
__global__ __launch_bounds__(256) void stats2_k(const float* __restrict__ s, const float* __restrict__ r,
                                                float* __restrict__ S)
{
    int t = threadIdx.x;
    int i = blockIdx.x * 256 + t;
    float sv = s[i], rv = r[i];
    float vals[5] = { sv, rv, sv * sv, rv * rv, sv * rv };
    __shared__ float buf[256];
    for (int q = 0; q < 5; q++) {
        buf[t] = vals[q];
        __syncthreads();
        for (int off = 128; off > 0; off >>= 1) {
            if (t < off) buf[t] += buf[t + off];
            __syncthreads();
        }
        if (t == 0) atomicAdd(&S[q], buf[0]);
        __syncthreads();
    }
}

// Z2 + edge_prob; wave per row; grid 2048 x 256
__global__ __launch_bounds__(256) void z2_edge_k(const float* __restrict__ s, const float* __restrict__ r,
                                                 const float* __restrict__ S,
                                                 const float* __restrict__ W2, const float* __restrict__ b2,
                                                 const float* __restrict__ g2, const float* __restrict__ bb2,
                                                 const float* __restrict__ eW, const float* __restrict__ eb,
                                                 const float* __restrict__ Z1,
                                                 float* __restrict__ Z2, float* __restrict__ edge_out)
{
    int w = threadIdx.x >> 6, lane = threadIdx.x & 63;
    int row = blockIdx.x * 4 + w;
    const float inv = 1.f / 8192.f;
    float ms = S[0] * inv, mr = S[1] * inv;
    float vs = S[2] * inv - ms * ms;
    float vr = S[3] * inv - mr * mr;
    float cv = S[4] * inv - ms * mr;
    float w2 = W2[lane], bz = b2[lane];
    float mc = w2 * ms + bz * mr;
    float vc = w2 * w2 * vs + 2.f * w2 * bz * cv + bz * bz * vr;
    float x  = w2 * s[row] + bz * r[row];
    float y  = fmaxf(g2[lane] * (x - mc) * rsqrtf(vc + 1e-5f) + bb2[lane], 0.f);
#pragma unroll
    for (int o = 32; o > 0; o >>= 1) y = fmaxf(y, __shfl_xor(y, o));
    if (lane == 0) {
        Z2[row] = y;
        float e = Z1[row] * eW[0] + y * eW[1] + eb[0];
        edge_out[row] = sigmoidf_(e);
    }
}

// H_e into Hcat cols 256/257 + node head; grid 4096 x 256
__global__ __launch_bounds__(256) void he_node_k(const float* __restrict__ B1, const float* __restrict__ Z1,
                                                 const float* __restrict__ Z2, float* __restrict__ hcat,
                                                 const float* __restrict__ nW, const float* __restrict__ nb,
                                                 float* __restrict__ node_out)
{
    int n = blockIdx.x, t = threadIdx.x;
    const f32x4* row = (const f32x4*)(B1 + (long)n * 8192);
    const f32x4* z1v = (const f32x4*)Z1;
    const f32x4* z2v = (const f32x4*)Z2;
    float a1 = 0.f, a2 = 0.f;
#pragma unroll
    for (int k = 0; k < 8; k++) {
        f32x4 v = row[t + 256 * k];
        f32x4 p = z1v[t + 256 * k];
        f32x4 q = z2v[t + 256 * k];
        a1 += v.x * p.x + v.y * p.y + v.z * p.z + v.w * p.w;
        a2 += v.x * q.x + v.y * q.y + v.z * q.z + v.w * q.w;
    }
    __shared__ float l1s[256], l2s[256];
    __shared__ float hv[2];
    l1s[t] = a1; l2s[t] = a2;
    __syncthreads();
    for (int off = 128; off > 0; off >>= 1) {
        if (t < off) { l1s[t] += l1s[t + off]; l2s[t] += l2s[t + off]; }
        __syncthreads();
    }
    if (t == 0) {
        hcat[(long)n * 258 + 256] = l1s[0];
        hcat[(long)n * 258 + 257] = l2s[0];
        hv[0] = l1s[0]; hv[1] = l2s[0];
    }
    __syncthreads();
    float d = hcat[(long)n * 258 + t] * nW[t];
    l1s[t] = d;
    __syncthreads();
    for (int off = 128; off > 0; off >>= 1) {
        if (t < off) l1s[t] += l1s[t + off];
        __syncthreads();
    }
    if (t == 0) {
        float tot = l1s[0] + hv[0] * nW[256] + hv[1] * nW[257] + nb[0];
        node_out[n] = sigmoidf_(tot);
    }
}

// hyperedge gather-mean-dot-sigmoid; wave per hyperedge; grid 256 x 256
__global__ __launch_bounds__(256) void hyper_k(const void* __restrict__ he_idx,
                                               const float* __restrict__ hcat,
                                               const float* __restrict__ hW, const float* __restrict__ hb,
                                               float* __restrict__ out)
{
    int w = threadIdx.x >> 6, lane = threadIdx.x & 63;
    int h = blockIdx.x * 4 + w;
    const unsigned int* u = (const unsigned int*)he_idx;
    // int64 detection: all high dwords of first 64 entries zero
    unsigned int odd = u[2 * lane + 1];
    bool is64 = __all(odd == 0u);
    float acc = 0.f;
    for (int k = 0; k < 8; k++) {
        int idx;
        if (is64) idx = (int)((const long long*)he_idx)[h * 8 + k];
        else      idx = ((const int*)he_idx)[h * 8 + k];
        const float* hr = hcat + (long)idx * 258;
        for (int d = lane; d < 258; d += 64) acc += hr[d] * hW[d];
    }
    acc *= 0.125f;
#pragma unroll
    for (int o = 32; o > 0; o >>= 1) acc += __shfl_xor(acc, o);
    if (lane == 0) out[h] = sigmoidf_(acc + hb[0]);
}

// ---------------------------------------------------------------------------
extern "C" void kernel_launch(void* const* d_in, const int* in_sizes, int n_in,
                              void* d_out, int out_size, void* d_ws, size_t ws_size,
                              hipStream_t stream)
{
    const float* X_n  = (const float*)d_in[0];
    const float* X_e  = (const float*)d_in[1];
    const float* A_t  = (const float*)d_in[2];
    const float* L1   = (const float*)d_in[3];
    const float* B1   = (const float*)d_in[4];
    const float* gW1  = (const float*)d_in[5];
    const float* gb1  = (const float*)d_in[6];
    const float* gW2  = (const float*)d_in[7];
    const float* gb2  = (const float*)d_in[8];
    const float* hW1  = (const float*)d_in[9];
    const float* hb1  = (const float*)d_in[10];
    const float* bn1g = (const float*)d_in[11];
    const float* bn1b = (const float*)d_in[12];
    const float* hW2  = (const float*)d_in[13];
    const float* hb2  = (const float*)d_in[14];
    const float* bn2g = (const float*)d_in[15];
    const float* bn2b = (const float*)d_in[16];
    const float* nW   = (const float*)d_in[17];
    const float* nb   = (const float*)d_in[18];
    const float* eW   = (const float*)d_in[19];
    const float* ebb  = (const float*)d_in[20];
    const float* yW   = (const float*)d_in[21];
    const float* yb   = (const float*)d_in[22];
    const void*  he   = d_in[23];

    float* out       = (float*)d_out;
    float* out_node  = out;              // 4096
    float* out_edge  = out + 4096;       // 8192
    float* out_hyper = out + 12288;      // 1024
    float* hcat      = out + 13312;      // 4096 x 258

    // workspace layout
    size_t off = 0;
    auto alloc = [&](size_t bytes) {
        void* p = (char*)d_ws + off;
        off = (off + bytes + 255) & ~(size_t)255;
        return p;
    };
    ushort* Xn_bf = (ushort*)alloc(4096 * 128 * 2);
    ushort* W1t   = (ushort*)alloc(128 * 256 * 2);
    ushort* W2t   = (ushort*)alloc(256 * 256 * 2);
    ushort* W1ht  = (ushort*)alloc(64 * 64 * 2);
    float*  C1    = (float*)alloc(4096 * 128 * 4);
    ushort* H_bf  = (ushort*)alloc(4096 * 256 * 2);
    float*  C2    = (float*)alloc(4096 * 256 * 4);
    ushort* Zt1   = (ushort*)alloc(8192 * 64 * 2);
    float*  Zc1   = (float*)alloc(8192 * 64 * 4);
    float*  stats = (float*)alloc(256 * 4);   // gsum[64], gsq[64], S5[5]
    float*  gsum  = stats;
    float*  gsq   = stats + 64;
    float*  S5    = stats + 128;
    float*  Z1    = (float*)alloc(8192 * 4);
    float*  Z2    = (float*)alloc(8192 * 4);
    float*  sbuf  = (float*)alloc(8192 * 4);
    float*  rbuf  = (float*)alloc(8192 * 4);
    float*  P     = (float*)alloc(2097152 * 4);  // split-K partials (8 MB)

    // prep
    zero_stats_k<<<1, 256, 0, stream>>>(stats);
    convert_bf16_k<<<512, 256, 0, stream>>>(X_n, Xn_bf, 4096 * 128 / 4);
    transpose_bf16_k<<<128, 256, 0, stream>>>(gW1, W1t, 256, 128);
    transpose_bf16_k<<<256, 256, 0, stream>>>(gW2, W2t, 256, 256);
    transpose_bf16_k<<<16, 256, 0, stream>>>(hW1, W1ht, 64, 64);

    // GNN
    gemm_kernel<true, false, false, false><<<dim3(32, 2, 4), 256, 0, stream>>>(
        A_t, Xn_bf, nullptr, P, nullptr, 4096, 128, 4096, 128, 1024);
    reduce_add<<<512, 256, 0, stream>>>(P, C1, 4096 * 128, 4);
    gemm_kernel<false, true, true, true><<<dim3(32, 4, 1), 256, 0, stream>>>(
        C1, W1t, gb1, nullptr, H_bf, 4096, 256, 128, 256, 0);
    gemm_kernel<true, false, false, false><<<dim3(32, 4, 2), 256, 0, stream>>>(
        A_t, H_bf, nullptr, P, nullptr, 4096, 256, 4096, 256, 2048);
    reduce_add<<<1024, 256, 0, stream>>>(P, C2, 4096 * 256, 2);
    gemm_kernel<false, true, false, true><<<dim3(32, 4, 1), 256, 0, stream>>>(
        C2, W2t, gb2, hcat, nullptr, 4096, 256, 256, 258, 0);

    // HoSC layer 1
    gemm_kernel<false, false, true, true><<<dim3(64, 1, 1), 256, 0, stream>>>(
        X_e, W1ht, hb1, nullptr, Zt1, 8192, 64, 64, 64, 0);
    gemm_kernel<true, false, false, false><<<dim3(64, 1, 4), 256, 0, stream>>>(
        L1, Zt1, nullptr, P, nullptr, 8192, 64, 8192, 64, 2048);
    reduce_add<<<512, 256, 0, stream>>>(P, Zc1, 8192 * 64, 4);
    bn_stats_k<<<64, 256, 0, stream>>>(Zc1, gsum, gsq);
    z1_k<<<2048, 256, 0, stream>>>(Zc1, gsum, gsq, bn1g, bn1b, Z1);

    // HoSC layer 2 (rank-1 collapse)
    pass2_k<<<8192, 256, 0, stream>>>(L1, Z1, sbuf, rbuf);
    stats2_k<<<32, 256, 0, stream>>>(sbuf, rbuf, S5);
    z2_edge_k<<<2048, 256, 0, stream>>>(sbuf, rbuf, S5, hW2, hb2, bn2g, bn2b,
                                        eW, ebb, Z1, Z2, out_edge);

    // fuse + heads
    he_node_k<<<4096, 256, 0, stream>>>(B1, Z1, Z2, hcat, nW, nb, out_node);
    hyper_k<<<256, 256, 0, stream>>>(he, hcat, yW, yb, out_hyper);
}